// Round 4
// baseline (4506.411 us; speedup 1.0000x reference)
//
#include <hip/hip_runtime.h>
#include <cstdint>
#include <cstddef>

namespace {

constexpr int kN = 50000;   // nodes
constexpr int kE = 800000;  // edges
constexpr float kInv3 = 0.57735026918962576451f; // 1/sqrt(3)
constexpr float kInv2 = 0.70710678118654752440f; // 1/sqrt(2)

__device__ __forceinline__ float bcast(float v, int k) {
  return __int_as_float(__builtin_amdgcn_readlane(__float_as_int(v), k));
}
__device__ __forceinline__ int bcasti(int v, int k) {
  return __builtin_amdgcn_readlane(v, k);
}
__device__ __forceinline__ float silu(float x) {
  return x / (1.0f + __expf(-x));
}
__device__ __forceinline__ uint32_t bf16r(float f) {  // round-to-nearest-even
  uint32_t u = __float_as_uint(f);
  return (u + 0x7fffu + ((u >> 16) & 1u)) >> 16;
}

// ---------------------------------------------------------------------------
// K1: h0 = x0 @ pre_W0 ; h1[:,:,m] = x1[:,:,m] @ pre_W1
// ---------------------------------------------------------------------------
__global__ __launch_bounds__(256) void k_pre(const float* __restrict__ nf,
                                             const float* __restrict__ W0,
                                             const float* __restrict__ W1,
                                             float4* __restrict__ hcomb) {
  __shared__ float sW[8192];
  __shared__ float sbuf[4][256];
  for (int i = threadIdx.x; i < 8192; i += 256)
    sW[i] = (i < 4096) ? W0[i] : W1[i - 4096];
  __syncthreads();

  const int wid = threadIdx.x >> 6, lane = threadIdx.x & 63;
  const int n = blockIdx.x * 4 + wid;
  if (n >= kN) return;
  const float4 rv = ((const float4*)nf)[(size_t)n * 64 + lane];
  *(float4*)&sbuf[wid][lane * 4] = rv;
  const float v0 = sbuf[wid][lane];
  const float vx = sbuf[wid][64 + 3 * lane];
  const float vy = sbuf[wid][64 + 3 * lane + 1];
  const float vz = sbuf[wid][64 + 3 * lane + 2];
  float a0 = 0.f, ax = 0.f, ay = 0.f, az = 0.f;
#pragma unroll
  for (int k = 0; k < 64; ++k) {
    const float w0 = sW[k * 64 + lane];
    const float w1 = sW[4096 + k * 64 + lane];
    a0 = fmaf(bcast(v0, k), w0, a0);
    ax = fmaf(bcast(vx, k), w1, ax);
    ay = fmaf(bcast(vy, k), w1, ay);
    az = fmaf(bcast(vz, k), w1, az);
  }
  hcomb[(size_t)n * 64 + lane] = make_float4(a0, ax, ay, az);
}

// ---------------------------------------------------------------------------
// CSR build
// ---------------------------------------------------------------------------
__global__ void k_hist(const int* __restrict__ ei, int* __restrict__ cnt) {
  const int e = blockIdx.x * blockDim.x + threadIdx.x;
  if (e < kE) atomicAdd(&cnt[ei[kE + e]], 1);
}

__global__ __launch_bounds__(1024) void k_scan(const int* __restrict__ cnt,
                                               int* __restrict__ starts) {
  __shared__ int sh[1024];
  const int t = threadIdx.x;
  constexpr int CH = 49;
  const int base = t * CH;
  int s = 0;
  for (int i = 0; i < CH; ++i) {
    const int idx = base + i;
    if (idx < kN) s += cnt[idx];
  }
  sh[t] = s;
  __syncthreads();
  for (int off = 1; off < 1024; off <<= 1) {
    const int v = sh[t];
    const int o = (t >= off) ? sh[t - off] : 0;
    __syncthreads();
    sh[t] = v + o;
    __syncthreads();
  }
  int run = sh[t] - s;
  for (int i = 0; i < CH; ++i) {
    const int idx = base + i;
    if (idx < kN) {
      starts[idx] = run;
      run += cnt[idx];
    }
  }
}

__global__ void k_scatter(const int* __restrict__ ei, int* __restrict__ cursor,
                          int* __restrict__ eids) {
  const int e = blockIdx.x * blockDim.x + threadIdx.x;
  if (e < kE) {
    const int pos = atomicAdd(&cursor[ei[kE + e]], 1);
    eids[pos] = e;
  }
}

// ---------------------------------------------------------------------------
// K2a (NEW): edge-parallel radial MLP. lane = edge. All weight reads are
// wave-uniform LDS broadcasts; all FMAs use per-lane registers. L1 fused
// into L2 accumulators to cap VGPR (~110). Output w packed bf16 [e][5][64],
// stores coalesced via per-wave LDS transpose tile (stride-5 u32, ~2-way).
// ---------------------------------------------------------------------------
__global__ __launch_bounds__(1024, 4) void k_mlp(const float* __restrict__ rb,
                                                 const float* __restrict__ W1f,
                                                 const float* __restrict__ W2f,
                                                 const float* __restrict__ W3f,
                                                 uint32_t* __restrict__ wout) {
  extern __shared__ float sm[];  // 25088 weights + 16*320 u32 transpose tiles
  for (int i = threadIdx.x; i < 25088; i += 1024) {
    float v;
    if (i < 512) v = W1f[i];
    else if (i < 4608) v = W2f[i - 512];
    else v = W3f[i - 4608];
    sm[i] = v;
  }
  __syncthreads();
  const float* sW1 = sm;
  const float* sW2 = sm + 512;
  const float* sW3 = sm + 4608;
  const int lane = threadIdx.x & 63, wid = threadIdx.x >> 6;
  uint32_t* T = (uint32_t*)(sm + 25088) + wid * 320;
  const int wt = blockIdx.x * 16 + wid;
  if (wt >= kE / 64) return;  // no barriers after this point
  const int e0 = wt * 64;
  const int e = e0 + lane;

  float x[8];
  {
    const float4 a = *(const float4*)(rb + (size_t)e * 8);
    const float4 b = *(const float4*)(rb + (size_t)e * 8 + 4);
    x[0] = a.x; x[1] = a.y; x[2] = a.z; x[3] = a.w;
    x[4] = b.x; x[5] = b.y; x[6] = b.z; x[7] = b.w;
  }

  float acc2[64];
#pragma unroll
  for (int u = 0; u < 64; ++u) acc2[u] = 0.f;

#pragma unroll 1
  for (int k8 = 0; k8 < 8; ++k8) {  // rolled: code-size control
    // ---- layer 1, units k8*8..k8*8+7 ----
    float h1c[8];
#pragma unroll
    for (int j = 0; j < 8; ++j) h1c[j] = 0.f;
#pragma unroll
    for (int kk = 0; kk < 8; ++kk) {
      const float4 wa = *(const float4*)(sW1 + kk * 64 + k8 * 8);
      const float4 wb = *(const float4*)(sW1 + kk * 64 + k8 * 8 + 4);
      h1c[0] = fmaf(x[kk], wa.x, h1c[0]);
      h1c[1] = fmaf(x[kk], wa.y, h1c[1]);
      h1c[2] = fmaf(x[kk], wa.z, h1c[2]);
      h1c[3] = fmaf(x[kk], wa.w, h1c[3]);
      h1c[4] = fmaf(x[kk], wb.x, h1c[4]);
      h1c[5] = fmaf(x[kk], wb.y, h1c[5]);
      h1c[6] = fmaf(x[kk], wb.z, h1c[6]);
      h1c[7] = fmaf(x[kk], wb.w, h1c[7]);
    }
#pragma unroll
    for (int j = 0; j < 8; ++j) h1c[j] = silu(h1c[j]);
    // ---- layer 2 partial: acc2[u] += h1c[j] * W2[k8*8+j][u] ----
#pragma unroll
    for (int j = 0; j < 8; ++j) {
      const float hv = h1c[j];
      const float* wrow = sW2 + (k8 * 8 + j) * 64;
#pragma unroll
      for (int u8 = 0; u8 < 8; ++u8) {
        const float4 wa = *(const float4*)(wrow + u8 * 8);
        const float4 wb = *(const float4*)(wrow + u8 * 8 + 4);
        acc2[u8 * 8 + 0] = fmaf(hv, wa.x, acc2[u8 * 8 + 0]);
        acc2[u8 * 8 + 1] = fmaf(hv, wa.y, acc2[u8 * 8 + 1]);
        acc2[u8 * 8 + 2] = fmaf(hv, wa.z, acc2[u8 * 8 + 2]);
        acc2[u8 * 8 + 3] = fmaf(hv, wa.w, acc2[u8 * 8 + 3]);
        acc2[u8 * 8 + 4] = fmaf(hv, wb.x, acc2[u8 * 8 + 4]);
        acc2[u8 * 8 + 5] = fmaf(hv, wb.y, acc2[u8 * 8 + 5]);
        acc2[u8 * 8 + 6] = fmaf(hv, wb.z, acc2[u8 * 8 + 6]);
        acc2[u8 * 8 + 7] = fmaf(hv, wb.w, acc2[u8 * 8 + 7]);
      }
    }
  }
#pragma unroll
  for (int u = 0; u < 64; ++u) acc2[u] = silu(acc2[u]);  // acc2 becomes h2

  // ---- layer 3: 40 chunks of 8 outputs; pack bf16; LDS transpose; store ----
  const int el = lane >> 2, jj = lane & 3;
#pragma unroll 1
  for (int c8 = 0; c8 < 40; ++c8) {
    float acc[8] = {0.f, 0.f, 0.f, 0.f, 0.f, 0.f, 0.f, 0.f};
#pragma unroll
    for (int k = 0; k < 64; ++k) {
      const float4 wa = *(const float4*)(sW3 + k * 320 + c8 * 8);
      const float4 wb = *(const float4*)(sW3 + k * 320 + c8 * 8 + 4);
      acc[0] = fmaf(acc2[k], wa.x, acc[0]);
      acc[1] = fmaf(acc2[k], wa.y, acc[1]);
      acc[2] = fmaf(acc2[k], wa.z, acc[2]);
      acc[3] = fmaf(acc2[k], wa.w, acc[3]);
      acc[4] = fmaf(acc2[k], wb.x, acc[4]);
      acc[5] = fmaf(acc2[k], wb.y, acc[5]);
      acc[6] = fmaf(acc2[k], wb.z, acc[6]);
      acc[7] = fmaf(acc2[k], wb.w, acc[7]);
    }
#pragma unroll
    for (int j = 0; j < 4; ++j)
      T[lane * 5 + j] = bf16r(acc[2 * j]) | (bf16r(acc[2 * j + 1]) << 16);
    // same-wave LDS RAW: in-order DS pipe, compiler inserts lgkmcnt
#pragma unroll
    for (int i = 0; i < 4; ++i) {
      const int ee = el + 16 * i;
      wout[(size_t)(e0 + ee) * 160 + c8 * 4 + jj] = T[ee * 5 + jj];
    }
  }
}

// ---------------------------------------------------------------------------
// K2b (NEW): slim consumer. Per-node aggregation; per edge: 5 bf16 w-loads,
// h row gather (prefetched), message math. No LDS, no MLP.
// ---------------------------------------------------------------------------
__global__ __launch_bounds__(1024, 6) void k_edge2(
    const float* __restrict__ sph, const int* __restrict__ ei,
    const int* __restrict__ eids, const int* __restrict__ ends,
    const int* __restrict__ cnts, const unsigned short* __restrict__ w16,
    const float4* __restrict__ hcomb, float4* __restrict__ tcomb) {
  const int lane = threadIdx.x & 63;
  const int gw = blockIdx.x * 16 + (threadIdx.x >> 6);
  for (int n = gw; n < kN; n += 512 * 16) {
    int tmp = 0;
    if (lane == 0) tmp = ends[n];
    else if (lane == 1) tmp = cnts[n];
    const int end = bcasti(tmp, 0);
    const int cn = bcasti(tmp, 1);
    float a0 = 0.f, axx = 0.f, ayy = 0.f, azz = 0.f;

    for (int base = end - cn; base < end; base += 64) {
      const int m = min(64, end - base);
      int ev = 0, sidv = 0;
      float4 svv = make_float4(0.f, 0.f, 0.f, 0.f);
      if (lane < m) {
        ev = eids[base + lane];
        sidv = ei[ev];
        svv = *(const float4*)(sph + (size_t)ev * 4);
      }
      // preload edge 0
      int ecur = bcasti(ev, 0), scur = bcasti(sidv, 0);
      float4 h = hcomb[(size_t)scur * 64 + lane];
      const unsigned short* wp = w16 + (size_t)ecur * 320 + lane;
      uint32_t u0 = wp[0], u1 = wp[64], u2 = wp[128], u3 = wp[192], u4 = wp[256];

      for (int j = 0; j < m; ++j) {
        float4 hn = h;
        uint32_t n0 = u0, n1 = u1, n2 = u2, n3 = u3, n4 = u4;
        if (j + 1 < m) {
          const int en = bcasti(ev, j + 1);
          const int sn = bcasti(sidv, j + 1);
          hn = hcomb[(size_t)sn * 64 + lane];
          const unsigned short* wq = w16 + (size_t)en * 320 + lane;
          n0 = wq[0]; n1 = wq[64]; n2 = wq[128]; n3 = wq[192]; n4 = wq[256];
        }
        const float y0 = bcast(svv.x, j), y1 = bcast(svv.y, j);
        const float y2 = bcast(svv.z, j), y3 = bcast(svv.w, j);
        const float w0 = __uint_as_float(u0 << 16);
        const float w1v = __uint_as_float(u1 << 16);
        const float w2v = __uint_as_float(u2 << 16);
        const float w3v = __uint_as_float(u3 << 16);
        const float w4v = __uint_as_float(u4 << 16);

        const float dot = h.y * y1 + h.z * y2 + h.w * y3;
        const float m0 = w0 * h.x * y0 + w1v * kInv3 * dot;
        const float cx = h.z * y3 - h.w * y2;
        const float cy = h.w * y1 - h.y * y3;
        const float cz = h.y * y2 - h.z * y1;
        const float t2 = w2v * h.x;
        const float c4 = w4v * kInv2;
        const float w3y0 = w3v * y0;
        a0 += m0;
        axx += t2 * y1 + w3y0 * h.y + c4 * cx;
        ayy += t2 * y2 + w3y0 * h.z + c4 * cy;
        azz += t2 * y3 + w3y0 * h.w + c4 * cz;
        h = hn; u0 = n0; u1 = n1; u2 = n2; u3 = n3; u4 = n4;
      }
    }
    tcomb[(size_t)n * 64 + lane] = make_float4(a0, axx, ayy, azz);
  }
}

// ---------------------------------------------------------------------------
// K2 (FALLBACK, used only if ws_size too small): fused MLP+aggregate (R3).
// ---------------------------------------------------------------------------
__global__ __launch_bounds__(1024, 4) void k_edge(
    const float* __restrict__ rb, const float* __restrict__ sph,
    const int* __restrict__ ei, const int* __restrict__ eids,
    const int* __restrict__ ends, const int* __restrict__ cnts,
    const float* __restrict__ W1, const float* __restrict__ W2,
    const float* __restrict__ W3, const float4* __restrict__ hcomb,
    float4* __restrict__ tcomb) {
  extern __shared__ float sm[];
  for (int i = threadIdx.x; i < 25088; i += 1024) {
    float v;
    int dst;
    if (i < 512) { v = W1[i]; dst = i; }
    else if (i < 4608) {
      const int j = i - 512;
      const int k = j >> 6, c = j & 63;
      v = W2[j];
      dst = 512 + c * 64 + (((k >> 2) ^ (c & 7)) << 2) + (k & 3);
    } else {
      const int j = i - 4608;
      const int k = j / 320, r = j - k * 320;
      const int q = r >> 6, c = r & 63;
      v = W3[j];
      dst = 4608 + q * 4096 + c * 64 + (((k >> 2) ^ (c & 7)) << 2) + (k & 3);
    }
    sm[dst] = v;
  }
  __syncthreads();

  const float* sW1 = sm;
  const float* sW2 = sm + 512;
  const float* sW3 = sm + 4608;
  const int lane = threadIdx.x & 63;
  const int gw = blockIdx.x * 16 + (threadIdx.x >> 6);
  const int rowoff = lane * 64;
  const int lsw = lane & 7;

  for (int n = gw; n < kN; n += 256 * 16) {
    int tmp = 0;
    if (lane == 0) tmp = ends[n];
    else if (lane == 1) tmp = cnts[n];
    const int end = bcasti(tmp, 0);
    const int cn = bcasti(tmp, 1);
    float a0 = 0.f, axx = 0.f, ayy = 0.f, azz = 0.f;

    for (int base = end - cn; base < end; base += 64) {
      const int m = min(64, end - base);
      int sidv = 0;
      float4 r0v = make_float4(0.f, 0.f, 0.f, 0.f);
      float4 r1v = r0v, svv = r0v;
      if (lane < m) {
        const int e = eids[base + lane];
        sidv = ei[e];
        r0v = *(const float4*)(rb + (size_t)e * 8);
        r1v = *(const float4*)(rb + (size_t)e * 8 + 4);
        svv = *(const float4*)(sph + (size_t)e * 4);
      }
      const int sid0 = bcasti(sidv, 0);
      float4 h = hcomb[(size_t)sid0 * 64 + lane];

      for (int j = 0; j < m; ++j) {
        float4 hn = h;
        if (j + 1 < m) {
          const int sn = bcasti(sidv, j + 1);
          hn = hcomb[(size_t)sn * 64 + lane];
        }
        const float e0 = bcast(r0v.x, j), e1 = bcast(r0v.y, j);
        const float e2 = bcast(r0v.z, j), e3 = bcast(r0v.w, j);
        const float e4 = bcast(r1v.x, j), e5 = bcast(r1v.y, j);
        const float e6 = bcast(r1v.z, j), e7 = bcast(r1v.w, j);
        const float y0 = bcast(svv.x, j), y1 = bcast(svv.y, j);
        const float y2 = bcast(svv.z, j), y3 = bcast(svv.w, j);

        float acc = e0 * sW1[lane];
        acc = fmaf(e1, sW1[64 + lane], acc);
        acc = fmaf(e2, sW1[128 + lane], acc);
        acc = fmaf(e3, sW1[192 + lane], acc);
        acc = fmaf(e4, sW1[256 + lane], acc);
        acc = fmaf(e5, sW1[320 + lane], acc);
        acc = fmaf(e6, sW1[384 + lane], acc);
        acc = fmaf(e7, sW1[448 + lane], acc);
        const float h1 = silu(acc);

        float acc2 = 0.f;
#pragma unroll
        for (int k4 = 0; k4 < 16; ++k4) {
          const float4 w = *(const float4*)(sW2 + rowoff + ((k4 ^ lsw) << 2));
          acc2 = fmaf(bcast(h1, 4 * k4 + 0), w.x, acc2);
          acc2 = fmaf(bcast(h1, 4 * k4 + 1), w.y, acc2);
          acc2 = fmaf(bcast(h1, 4 * k4 + 2), w.z, acc2);
          acc2 = fmaf(bcast(h1, 4 * k4 + 3), w.w, acc2);
        }
        const float h2 = silu(acc2);

        float w0 = 0.f, w1v = 0.f, w2v = 0.f, w3v = 0.f, w4v = 0.f;
#pragma unroll 4
        for (int k4 = 0; k4 < 16; ++k4) {
          const int off = rowoff + ((k4 ^ lsw) << 2);
          const float4 p0 = *(const float4*)(sW3 + off);
          const float4 p1 = *(const float4*)(sW3 + 4096 + off);
          const float4 p2 = *(const float4*)(sW3 + 8192 + off);
          const float4 p3 = *(const float4*)(sW3 + 12288 + off);
          const float4 p4 = *(const float4*)(sW3 + 16384 + off);
          const float k0 = bcast(h2, 4 * k4 + 0);
          const float k1 = bcast(h2, 4 * k4 + 1);
          const float k2 = bcast(h2, 4 * k4 + 2);
          const float k3 = bcast(h2, 4 * k4 + 3);
          w0 = fmaf(k0, p0.x, w0); w0 = fmaf(k1, p0.y, w0);
          w0 = fmaf(k2, p0.z, w0); w0 = fmaf(k3, p0.w, w0);
          w1v = fmaf(k0, p1.x, w1v); w1v = fmaf(k1, p1.y, w1v);
          w1v = fmaf(k2, p1.z, w1v); w1v = fmaf(k3, p1.w, w1v);
          w2v = fmaf(k0, p2.x, w2v); w2v = fmaf(k1, p2.y, w2v);
          w2v = fmaf(k2, p2.z, w2v); w2v = fmaf(k3, p2.w, w2v);
          w3v = fmaf(k0, p3.x, w3v); w3v = fmaf(k1, p3.y, w3v);
          w3v = fmaf(k2, p3.z, w3v); w3v = fmaf(k3, p3.w, w3v);
          w4v = fmaf(k0, p4.x, w4v); w4v = fmaf(k1, p4.y, w4v);
          w4v = fmaf(k2, p4.z, w4v); w4v = fmaf(k3, p4.w, w4v);
        }

        const float dot = h.y * y1 + h.z * y2 + h.w * y3;
        const float m0 = w0 * h.x * y0 + w1v * kInv3 * dot;
        const float cx = h.z * y3 - h.w * y2;
        const float cy = h.w * y1 - h.y * y3;
        const float cz = h.y * y2 - h.z * y1;
        const float t2 = w2v * h.x;
        const float c4 = w4v * kInv2;
        const float w3y0 = w3v * y0;
        a0 += m0;
        axx += t2 * y1 + w3y0 * h.y + c4 * cx;
        ayy += t2 * y2 + w3y0 * h.z + c4 * cy;
        azz += t2 * y3 + w3y0 * h.w + c4 * cz;
        h = hn;
      }
    }
    tcomb[(size_t)n * 64 + lane] = make_float4(a0, axx, ayy, azz);
  }
}

// ---------------------------------------------------------------------------
// K3a: self-connection einsums; 4 nodes per wave to amortize weight stream 4x.
// ---------------------------------------------------------------------------
__global__ __launch_bounds__(1024, 2) void k_sc(const float* __restrict__ nf,
                                                const float* __restrict__ attrs,
                                                const float* __restrict__ scW0,
                                                const float* __restrict__ scW1,
                                                float4* __restrict__ scout) {
  extern __shared__ float sm[];  // 10240 weights + 16*256 staging
  float* s0 = sm;
  float* s1 = sm + 5120;
  const int lane = threadIdx.x & 63, wid = threadIdx.x >> 6;
  float* sb = sm + 10240 + wid * 256;
  for (int nb = blockIdx.x * 64; nb < kN; nb += 391 * 64) {
    const int n0 = nb + wid * 4;
    float xr0[4], x1x[4], x1y[4], x1z[4];
#pragma unroll
    for (int j = 0; j < 4; ++j) {
      xr0[j] = x1x[j] = x1y[j] = x1z[j] = 0.f;
      if (n0 + j < kN) {
        const float4 rv = ((const float4*)nf)[(size_t)(n0 + j) * 64 + lane];
        *(float4*)&sb[lane * 4] = rv;
        xr0[j] = sb[lane];
        x1x[j] = sb[64 + 3 * lane];
        x1y[j] = sb[64 + 3 * lane + 1];
        x1z[j] = sb[64 + 3 * lane + 2];
      }
    }
    float avl = 0.f;
    const int nvalid = min(4, max(0, kN - n0));
    if (lane < nvalid * 10) avl = attrs[(size_t)n0 * 10 + lane];
    float at[4][10];
#pragma unroll
    for (int j = 0; j < 4; ++j)
#pragma unroll
      for (int a = 0; a < 10; ++a) at[j][a] = bcast(avl, j * 10 + a);

    float a0[4] = {0, 0, 0, 0}, axx[4] = {0, 0, 0, 0};
    float ayy[4] = {0, 0, 0, 0}, azz[4] = {0, 0, 0, 0};
    for (int ck = 0; ck < 8; ++ck) {
      __syncthreads();
      for (int i = threadIdx.x; i < 5120; i += 1024) {
        s0[i] = scW0[ck * 5120 + i];
        s1[i] = scW1[ck * 5120 + i];
      }
      __syncthreads();
#pragma unroll
      for (int k = 0; k < 8; ++k) {
        const int kg = ck * 8 + k;
        float t0[4] = {0, 0, 0, 0}, t1[4] = {0, 0, 0, 0};
#pragma unroll
        for (int a = 0; a < 10; ++a) {
          const float v0 = s0[k * 640 + a * 64 + lane];
          const float v1 = s1[k * 640 + a * 64 + lane];
#pragma unroll
          for (int j = 0; j < 4; ++j) {
            t0[j] = fmaf(at[j][a], v0, t0[j]);
            t1[j] = fmaf(at[j][a], v1, t1[j]);
          }
        }
#pragma unroll
        for (int j = 0; j < 4; ++j) {
          a0[j] = fmaf(bcast(xr0[j], kg), t0[j], a0[j]);
          axx[j] = fmaf(bcast(x1x[j], kg), t1[j], axx[j]);
          ayy[j] = fmaf(bcast(x1y[j], kg), t1[j], ayy[j]);
          azz[j] = fmaf(bcast(x1z[j], kg), t1[j], azz[j]);
        }
      }
    }
#pragma unroll
    for (int j = 0; j < 4; ++j)
      if (n0 + j < kN)
        scout[(size_t)(n0 + j) * 64 + lane] =
            make_float4(a0[j], axx[j], ayy[j], azz[j]);
  }
}

// ---------------------------------------------------------------------------
// K3b: lin transforms, gated nonlinearity, + self-connection, fin transforms.
// ---------------------------------------------------------------------------
__global__ __launch_bounds__(1024, 1) void k_post(
    const float* __restrict__ attrs,
    const float* __restrict__ lin0, const float* __restrict__ lin1,
    const float* __restrict__ c0w, const float* __restrict__ c1w,
    const float* __restrict__ fin0, const float* __restrict__ fin1,
    const float4* __restrict__ tcomb, const float4* __restrict__ scout,
    float4* __restrict__ out) {
  extern __shared__ float sm[];
  float* sl0 = sm;
  float* sl1 = sm + 4096;
  float* sf0 = sm + 8192;
  float* sf1 = sm + 12288;
  __shared__ float sc0[1920];
  __shared__ float sc1[1280];
  for (int i = threadIdx.x; i < 4096; i += 1024) {
    sl0[i] = lin0[i];
    sl1[i] = lin1[i];
    sf0[i] = fin0[i];
    sf1[i] = fin1[i];
  }
  for (int i = threadIdx.x; i < 1920; i += 1024) sc0[i] = c0w[i];
  for (int i = threadIdx.x; i < 1280; i += 1024) sc1[i] = c1w[i];
  __syncthreads();

  const int lane = threadIdx.x & 63;
  float* sb = sm + 16384 + (threadIdx.x >> 6) * 256;
  for (int n = blockIdx.x * 16 + (threadIdx.x >> 6); n < kN; n += 512 * 16) {
    const float4 t = tcomb[(size_t)n * 64 + lane];
    float avl = 0.f;
    if (lane < 10) avl = attrs[(size_t)n * 10 + lane];
    float b0 = 0.f, bx = 0.f, by = 0.f, bz = 0.f;
#pragma unroll
    for (int k = 0; k < 64; ++k) {
      const float w0 = sl0[k * 64 + lane];
      const float w1 = sl1[k * 64 + lane];
      b0 = fmaf(bcast(t.x, k), w0, b0);
      bx = fmaf(bcast(t.y, k), w1, bx);
      by = fmaf(bcast(t.z, k), w1, by);
      bz = fmaf(bcast(t.w, k), w1, bz);
    }
    float cw00 = 0.f, cw01 = 0.f, cw02 = 0.f, cw10 = 0.f, cw11 = 0.f;
#pragma unroll
    for (int a = 0; a < 10; ++a) {
      const float av = bcast(avl, a);
      cw00 = fmaf(av, sc0[a * 192 + lane], cw00);
      cw01 = fmaf(av, sc0[a * 192 + 64 + lane], cw01);
      cw02 = fmaf(av, sc0[a * 192 + 128 + lane], cw02);
      cw10 = fmaf(av, sc1[a * 128 + lane], cw10);
      cw11 = fmaf(av, sc1[a * 128 + 64 + lane], cw11);
    }
    const float4 sc = scout[(size_t)n * 64 + lane];
    const float o0 = cw00 * b0 + cw01 * b0 * b0 +
                     cw02 * (bx * bx + by * by + bz * bz) + sc.x;
    const float o1x = cw10 * bx + cw11 * b0 * bx + sc.y;
    const float o1y = cw10 * by + cw11 * b0 * by + sc.z;
    const float o1z = cw10 * bz + cw11 * b0 * bz + sc.w;
    float f0 = 0.f, fx = 0.f, fy = 0.f, fz = 0.f;
#pragma unroll
    for (int k = 0; k < 64; ++k) {
      const float w0 = sf0[k * 64 + lane];
      const float w1 = sf1[k * 64 + lane];
      f0 = fmaf(bcast(o0, k), w0, f0);
      fx = fmaf(bcast(o1x, k), w1, fx);
      fy = fmaf(bcast(o1y, k), w1, fy);
      fz = fmaf(bcast(o1z, k), w1, fz);
    }
    sb[lane] = f0;
    sb[64 + 3 * lane] = fx;
    sb[64 + 3 * lane + 1] = fy;
    sb[64 + 3 * lane + 2] = fz;
    out[(size_t)n * 64 + lane] = *(const float4*)&sb[lane * 4];
  }
}

}  // namespace

extern "C" void kernel_launch(void* const* d_in, const int* in_sizes, int n_in,
                              void* d_out, int out_size, void* d_ws,
                              size_t ws_size, hipStream_t stream) {
  (void)in_sizes; (void)n_in; (void)out_size;
  const float* nf = (const float*)d_in[0];
  const float* attrs = (const float*)d_in[1];
  const float* sph = (const float*)d_in[2];
  const float* rb = (const float*)d_in[3];
  const int* ei = (const int*)d_in[4];
  const float* preW0 = (const float*)d_in[5];
  const float* preW1 = (const float*)d_in[6];
  const float* mW1 = (const float*)d_in[7];
  const float* mW2 = (const float*)d_in[8];
  const float* mW3 = (const float*)d_in[9];
  const float* lin0 = (const float*)d_in[10];
  const float* lin1 = (const float*)d_in[11];
  const float* c0w = (const float*)d_in[12];
  const float* c1w = (const float*)d_in[13];
  const float* scW0 = (const float*)d_in[14];
  const float* scW1 = (const float*)d_in[15];
  const float* fin0 = (const float*)d_in[16];
  const float* fin1 = (const float*)d_in[17];
  float4* out = (float4*)d_out;

  char* ws = (char*)d_ws;
  const bool big = (ws_size >= 618000000ull);

  if (big) {
    uint32_t* wbuf = (uint32_t*)ws;                  // 512MB bf16 w [e][5][64]
    float4* hcomb = (float4*)(ws + 512000000);       // 51.2MB (reused as scout)
    float4* tcomb = (float4*)(ws + 563200000);       // 51.2MB
    int* cnts = (int*)(ws + 614400000);
    int* starts = (int*)(ws + 614600000);
    int* eids = (int*)(ws + 614800000);
    float4* scout = hcomb;

    hipMemsetAsync(cnts, 0, kN * sizeof(int), stream);
    k_pre<<<(kN + 3) / 4, 256, 0, stream>>>(nf, preW0, preW1, hcomb);
    k_hist<<<(kE + 255) / 256, 256, 0, stream>>>(ei, cnts);
    k_scan<<<1, 1024, 0, stream>>>(cnts, starts);
    k_scatter<<<(kE + 255) / 256, 256, 0, stream>>>(ei, starts, eids);

    hipFuncSetAttribute((const void*)k_mlp,
                        hipFuncAttributeMaxDynamicSharedMemorySize, 120832);
    k_mlp<<<(kE / 64 + 15) / 16, 1024, 120832, stream>>>(rb, mW1, mW2, mW3,
                                                         wbuf);
    k_edge2<<<512, 1024, 0, stream>>>(sph, ei, eids, starts, cnts,
                                      (const unsigned short*)wbuf, hcomb,
                                      tcomb);

    hipFuncSetAttribute((const void*)k_sc,
                        hipFuncAttributeMaxDynamicSharedMemorySize, 14336 * 4);
    k_sc<<<391, 1024, 14336 * 4, stream>>>(nf, attrs, scW0, scW1, scout);

    hipFuncSetAttribute((const void*)k_post,
                        hipFuncAttributeMaxDynamicSharedMemorySize, 20480 * 4);
    k_post<<<512, 1024, 20480 * 4, stream>>>(attrs, lin0, lin1, c0w, c1w,
                                             fin0, fin1, tcomb, scout, out);
  } else {
    float4* hcomb = (float4*)ws;
    float4* tcomb = (float4*)(ws + 51200000);
    int* cnts = (int*)(ws + 102400000);
    int* starts = (int*)(ws + 102600000);
    int* eids = (int*)(ws + 102800000);
    float4* scout = hcomb;

    hipMemsetAsync(cnts, 0, kN * sizeof(int), stream);
    k_pre<<<(kN + 3) / 4, 256, 0, stream>>>(nf, preW0, preW1, hcomb);
    k_hist<<<(kE + 255) / 256, 256, 0, stream>>>(ei, cnts);
    k_scan<<<1, 1024, 0, stream>>>(cnts, starts);
    k_scatter<<<(kE + 255) / 256, 256, 0, stream>>>(ei, starts, eids);

    hipFuncSetAttribute((const void*)k_edge,
                        hipFuncAttributeMaxDynamicSharedMemorySize, 25088 * 4);
    k_edge<<<256, 1024, 25088 * 4, stream>>>(rb, sph, ei, eids, starts, cnts,
                                             mW1, mW2, mW3, hcomb, tcomb);

    hipFuncSetAttribute((const void*)k_sc,
                        hipFuncAttributeMaxDynamicSharedMemorySize, 14336 * 4);
    k_sc<<<391, 1024, 14336 * 4, stream>>>(nf, attrs, scW0, scW1, scout);

    hipFuncSetAttribute((const void*)k_post,
                        hipFuncAttributeMaxDynamicSharedMemorySize, 20480 * 4);
    k_post<<<512, 1024, 20480 * 4, stream>>>(attrs, lin0, lin1, c0w, c1w,
                                             fin0, fin1, tcomb, scout, out);
  }
}